// Round 1
// baseline (313.156 us; speedup 1.0000x reference)
//
#include <hip/hip_runtime.h>

// ApsUp: polyphase 2x upsample (per-batch phase) + circular pad + depthwise
// 3x3 binomial blur, fused into a single gather kernel.
//
// Closed form per output (oy,ox), phase p (r=p&1, c=p>>1):
//   u=(oy-r)&127 -> rows i0=u>>1, i1=((u+1)&127)>>1 (dup when u even = weight 2)
//   v=(ox-c)&127 -> cols analogously; out = sum of 4 taps * 1/16.
//
// v2 remap: one thread = ONE output float4 (was 8 floats / 2 strided float4s).
//   Store: lane l of a wave writes out4[base + l] -> each global_store_dwordx4
//   covers a fully contiguous 1024 B (8 complete 128 B lines). The previous
//   version interleaved two NT stores at 32 B stride, so every cache line was
//   built from two instructions as 16 B halves -> partial-line NT writes.
//   Loads: float2 per blur row (cols 2j4, 2j4+1); 32-lane row group reads a
//   contiguous 256 B row segment. Neighbor column sum via one __shfl rotate
//   inside the 32-lane row group (circular wrap comes free).
//   phase[] is indexed by blockIdx-only math so p/r/c live in SGPRs.

typedef float v4f __attribute__((ext_vector_type(4)));
typedef float v2f __attribute__((ext_vector_type(2)));

__global__ __launch_bounds__(256) void aps_up_kernel(
    const float* __restrict__ inp,     // [16,256,64,64]
    const int*   __restrict__ phase,   // [16]
    float*       __restrict__ out)     // [16,256,128,128]
{
    const int g = blockIdx.x * 256 + threadIdx.x;  // one thread = 1 output float4

    const int j4    = g & 31;          // output float4-col (32 per 128-col row)
    const int oy    = (g >> 5) & 127;  // output row
    const int plane = g >> 12;         // b*256 + ch (4096 threads per plane; 16 blocks, no straddle)

    // batch index from blockIdx only: 4096 blocks per batch -> uniform, scalar load
    const int b = blockIdx.x >> 12;

    const int p = phase[b];
    const int r = p & 1;
    const int c = p >> 1;              // block-uniform -> no divergence

    // blur rows (vertical [1,2,1] folded: duplicate row when u even)
    const int u  = (oy - r) & 127;
    const int i0 = u >> 1;
    const int i1 = ((u + 1) & 127) >> 1;   // wraps 127 -> row 0

    const v2f* basef2 = reinterpret_cast<const v2f*>(inp) + (size_t)plane * 2048;
    const v2f a = basef2[i0 * 32 + j4];    // input cols 2j4, 2j4+1 of row i0
    const v2f d = basef2[i1 * 32 + j4];    // ... row i1 (== i0 when u even)

    // column sums over the two blur rows
    const v2f s = a + d;
    const float s0 = s.x, s1 = s.y;

    const int lane = threadIdx.x & 63;
    const int grp  = lane & 32;        // base of this 32-lane row group

    v4f o;
    if (c == 0) {
        // out cols 4j4..4j4+3, v = ox: need s[2j4+2] = next lane's s0
        // (lane j4=31 wraps to lane 0 of the group = input col 0)
        const int src = grp | ((j4 + 1) & 31);
        const float s2 = __shfl(s0, src, 64);
        o = (v4f){s0 + s0, s0 + s1, s1 + s1, s1 + s2};
    } else {
        // v = ox-1: need s[2j4-1] = prev lane's s1 (lane 0 wraps to lane 31 = col 63)
        const int src = grp | ((j4 - 1) & 31);
        const float sm1 = __shfl(s1, src, 64);
        o = (v4f){sm1 + s0, s0 + s0, s0 + s1, s1 + s1};
    }
    o *= 0.0625f;

    // contiguous per-instruction wave footprint: lane l -> out4[g], 1024 B/wave
    __builtin_nontemporal_store(o, reinterpret_cast<v4f*>(out) + g);
}

extern "C" void kernel_launch(void* const* d_in, const int* in_sizes, int n_in,
                              void* d_out, int out_size, void* d_ws, size_t ws_size,
                              hipStream_t stream) {
    const float* inp   = (const float*)d_in[0];
    const int*   phase = (const int*)d_in[1];
    float*       out   = (float*)d_out;

    // out_size = 16*256*128*128 = 67,108,864 floats; 4 per thread
    const int total_threads = out_size / 4;            // 16,777,216
    const int block = 256;
    const int grid  = total_threads / block;           // 65,536
    aps_up_kernel<<<grid, block, 0, stream>>>(inp, phase, out);
}

// Round 2
// 303.124 us; speedup vs baseline: 1.0331x; 1.0331x over previous
//
#include <hip/hip_runtime.h>

// ApsUp: polyphase 2x upsample (per-batch phase) + circular pad + depthwise
// 3x3 binomial blur, fused into a single gather kernel.
//
// Closed form per output (oy,ox), phase p (r=p&1, c=p>>1):
//   u=(oy-r)&127 -> rows i0=u>>1, i1=((u+1)&127)>>1 (dup when u even = weight 2)
//   v=(ox-c)&127 -> cols analogously; out = sum of 4 taps * 1/16.
//
// v3: PLAIN stores (drop nontemporal) + row-pair per thread.
//   - Theory: nt-hint stores bypass normal L2 write-combining and plateau
//     ~2.3 TB/s; the rocclr fill achieves 6.4 TB/s on the same linear
//     pattern with plain stores. (Round-1 showed strided-vs-contiguous NT
//     stores are neutral -> instruction pattern was never the limiter.)
//   - Row-pair: output rows u=2k,2k+1 need only input rows k,k+1:
//       s(u=2k)   = 2*row_k      (vertical taps collapse)
//       s(u=2k+1) = row_k + row_{k+1}
//     -> 2 float2 loads produce 2 output float4s (was 2 loads per 1).
//   - Stores: lane l of each 32-lane group writes a full row segment;
//     every global_store_dwordx4 covers full 128B lines (512B per group).

typedef float v4f __attribute__((ext_vector_type(4)));
typedef float v2f __attribute__((ext_vector_type(2)));

__global__ __launch_bounds__(256) void aps_up_kernel(
    const float* __restrict__ inp,     // [16,256,64,64]
    const int*   __restrict__ phase,   // [16]
    float*       __restrict__ out)     // [16,256,128,128]
{
    const int g = blockIdx.x * 256 + threadIdx.x;  // one thread = 2 output float4s

    const int j4    = g & 31;          // float4-col (32 per 128-col output row)
    const int k     = (g >> 5) & 63;   // input row pair index (u = 2k, 2k+1)
    const int plane = g >> 11;         // b*256 + ch (2048 threads/plane; 8 blocks, no straddle)

    // batch from blockIdx only: 2048 blocks per batch -> uniform scalar load
    const int b = blockIdx.x >> 11;

    const int p = phase[b];
    const int r = p & 1;
    const int c = p >> 1;              // block-uniform -> no divergence

    const v2f* basef2 = reinterpret_cast<const v2f*>(inp) + (size_t)plane * 2048;
    const v2f vk  = basef2[k * 32 + j4];               // row k,   cols 2j4..2j4+1
    const v2f vk1 = basef2[((k + 1) & 63) * 32 + j4];  // row k+1 (wrap 63->0)

    // vertical blur column sums for the two output rows of this pair
    const v2f sA = vk + vk;            // u = 2k   (row k duplicated, weight 2)
    const v2f sB = vk + vk1;           // u = 2k+1

    const int lane = threadIdx.x & 63;
    const int grp  = lane & 32;        // base of this 32-lane row group

    v4f oA, oB;
    if (c == 0) {
        // need s[2j4+2] = next lane's .x (lane 31 wraps to lane 0 = col 0)
        const int src = grp | ((j4 + 1) & 31);
        const float nA = __shfl(sA.x, src, 64);
        const float nB = __shfl(sB.x, src, 64);
        oA = (v4f){sA.x + sA.x, sA.x + sA.y, sA.y + sA.y, sA.y + nA};
        oB = (v4f){sB.x + sB.x, sB.x + sB.y, sB.y + sB.y, sB.y + nB};
    } else {
        // need s[2j4-1] = prev lane's .y (lane 0 wraps to lane 31 = col 63)
        const int src = grp | ((j4 - 1) & 31);
        const float mA = __shfl(sA.y, src, 64);
        const float mB = __shfl(sB.y, src, 64);
        oA = (v4f){mA + sA.x, sA.x + sA.x, sA.x + sA.y, sA.y + sA.y};
        oB = (v4f){mB + sB.x, sB.x + sB.x, sB.x + sB.y, sB.y + sB.y};
    }
    oA *= 0.0625f;
    oB *= 0.0625f;

    const int oyA = (2 * k + r) & 127;
    const int oyB = (2 * k + 1 + r) & 127;

    v4f* outp = reinterpret_cast<v4f*>(out) + (size_t)plane * 4096;
    outp[oyA * 32 + j4] = oA;          // plain stores: keep L2 write-combining
    outp[oyB * 32 + j4] = oB;
}

extern "C" void kernel_launch(void* const* d_in, const int* in_sizes, int n_in,
                              void* d_out, int out_size, void* d_ws, size_t ws_size,
                              hipStream_t stream) {
    const float* inp   = (const float*)d_in[0];
    const int*   phase = (const int*)d_in[1];
    float*       out   = (float*)d_out;

    // out_size = 16*256*128*128 = 67,108,864 floats; 8 per thread (2 float4)
    const int total_threads = out_size / 8;            // 8,388,608
    const int block = 256;
    const int grid  = total_threads / block;           // 32,768
    aps_up_kernel<<<grid, block, 0, stream>>>(inp, phase, out);
}